// Round 4
// baseline (57.384 us; speedup 1.0000x reference)
//
#include <hip/hip_runtime.h>
#include <float.h>
#include <math.h>

#define NJ   24
#define COL  14
#define CC   196        // COL*COL
#define CC3  2744       // COL^3
#define NV4_3D 686      // CC3/4
#define NV4_2D 49       // CC/4
#define TMPW 3
#define PPB  4          // pairs (waves) per block

// Single fused kernel.
// Per-pair math identity: sum_e (h[e]-tt[e])^2 = sum_e h^2 - sum_window g*(2h-g).
// Each wave handles one (b,j) pair; 4 waves/block combine in LDS to one 32B
// f32 partial per block; the last block (ticket atomic) tree-reduces all
// partials in f64 and writes the scalar loss.
__global__ __launch_bounds__(256)
void msed_fused_kernel(const float* __restrict__ o,
                       const float* __restrict__ h,
                       const float* __restrict__ o3D,
                       const float* __restrict__ h3D,
                       const float* __restrict__ t,
                       const float* __restrict__ t3D,
                       const float* __restrict__ v,
                       float* __restrict__ part,          // nblocks * 8 floats
                       unsigned int* __restrict__ counter,
                       float* __restrict__ out,
                       int npairs, int nblocks)
{
    const int wv   = threadIdx.x >> 6;
    const int lane = threadIdx.x & 63;
    const int pair = blockIdx.x * PPB + wv;

    __shared__ float warr[PPB][6];
    __shared__ int   lastFlag;

    float p0 = 0.f, p1 = 0.f, p2 = 0.f, p3 = 0.f, p4 = 0.f, p5 = 0.f;

    if (pair < npairs) {
        // ---- scalar prologue (wave-uniform) ----
        const float tx  = t[pair * 2 + 0];
        const float ty  = t[pair * 2 + 1];
        const float t3x = t3D[pair * 3 + 0];
        const float t3y = t3D[pair * 3 + 1];
        const float t3z = t3D[pair * 3 + 2];
        const float v0  = v[pair * 3 + 0];
        const float v1  = v[pair * 3 + 1];
        const float v2c = v[pair * 3 + 2];
        const bool vis = (v0 == 1.0f);

        const int mux = (int)floorf(tx * (float)COL + 0.5f);
        const int muy = (int)floorf(ty * (float)COL + 0.5f);
        const bool valid2d = !((mux - TMPW >= COL) || (muy - TMPW >= COL) ||
                               (mux + TMPW + 1 <= 0) || (muy + TMPW + 1 <= 0));

        const int m3x = (int)floorf(t3x * (float)COL + 0.5f);
        const int m3y = (int)floorf(t3y * (float)COL + 0.5f);
        const int m3z = (int)floorf(t3z * (float)COL + 7.0f + 0.5f);
        const bool valid3d = !((m3x - TMPW >= COL) || (m3y - TMPW >= COL) || (m3z - TMPW >= COL) ||
                               (m3x + TMPW + 1 < 0) || (m3y + TMPW + 1 < 0) || (m3z + TMPW + 1 < 0));

        const float keep = vis ? ((valid2d && valid3d) ? 1.0f : 0.0f) : 1.0f;
        const float vf0 = v0 * keep, vf1 = v1 * keep, vf2 = v2c * keep;
        const bool jm     = (vf0 != 0.0f);
        const bool active = jm || (vf1 != 0.0f) || (vf2 != 0.0f);
        const bool gate2  = vis && valid2d;
        const bool gate3  = vis && valid2d && valid3d;

        if (active) {
            // ---- streaming 3D: sum h^2 + argmax (no per-element decode) ----
            const float4* hp3 = (const float4*)(h3D + (size_t)pair * CC3);
            float s3 = 0.0f;
            float bv3 = -FLT_MAX; int bi3 = 0x7FFFFFFF;
            #pragma unroll
            for (int u = 0; u < 11; ++u) {
                const int i = lane + (u << 6);
                const bool valid = (u < 10) || (lane < (NV4_3D - 640));
                const int ic = valid ? i : lane;
                float4 q = hp3[ic];
                float vals[4] = {q.x, q.y, q.z, q.w};
                const int e0 = ic * 4;
                #pragma unroll
                for (int c = 0; c < 4; ++c) {
                    float hv = vals[c];
                    if (valid) {
                        s3 += hv * hv;
                        if (hv > bv3) { bv3 = hv; bi3 = e0 + c; }
                    }
                }
            }

            // ---- streaming 2D ----
            float s1 = 0.0f;
            float bv2 = -FLT_MAX; int bi2 = 0x7FFFFFFF;
            if (lane < NV4_2D) {
                const float4* hp2 = (const float4*)(h + (size_t)pair * CC);
                float4 q = hp2[lane];
                float vals[4] = {q.x, q.y, q.z, q.w};
                const int e0 = lane * 4;
                #pragma unroll
                for (int c = 0; c < 4; ++c) {
                    float hv = vals[c];
                    s1 += hv * hv;
                    if (hv > bv2) { bv2 = hv; bi2 = e0 + c; }
                }
            }

            // ---- gaussian window corrections (L1/L2-hot gathers) ----
            if (lane < 49) {
                const int dx = lane % 7 - TMPW;
                const int dy = lane / 7 - TMPW;
                const float gxy = __expf(-0.5f * (float)(dx * dx + dy * dy));

                if (gate2) {
                    const int x = mux + dx, y = muy + dy;
                    if ((unsigned)x < COL && (unsigned)y < COL) {
                        const float wh = h[(size_t)pair * CC + y * COL + x];
                        s1 += gxy * (gxy - 2.0f * wh);
                    }
                }
                if (gate3) {
                    const int x = m3x + dx, y = m3y + dy;
                    if ((unsigned)x < COL && (unsigned)y < COL) {
                        const float* base = h3D + (size_t)pair * CC3 + y * COL + x;
                        #pragma unroll
                        for (int dz = -TMPW; dz <= TMPW; ++dz) {
                            const int z = m3z + dz;
                            if ((unsigned)z < COL) {
                                const float g = gxy * __expf(-0.5f * (float)(dz * dz));
                                const float wh = base[z * CC];
                                s3 += g * (g - 2.0f * wh);
                            }
                        }
                    }
                }
            }

            // ---- single-wave shuffle reduction ----
            #pragma unroll
            for (int off = 32; off > 0; off >>= 1) {
                s3 += __shfl_down(s3, off);
                s1 += __shfl_down(s1, off);
                float ov = __shfl_down(bv3, off); int oi = __shfl_down(bi3, off);
                if (ov > bv3 || (ov == bv3 && oi < bi3)) { bv3 = ov; bi3 = oi; }
                float ow = __shfl_down(bv2, off); int oj = __shfl_down(bi2, off);
                if (ow > bv2 || (ow == bv2 && oj < bi2)) { bv2 = ow; bi2 = oj; }
            }

            if (lane == 0) {
                const int b = pair / NJ;
                const int j = pair - b * NJ;
                const float scale = 1.0f / (float)COL;

                const int am = bi2;
                const int x2 = am % COL, y2 = am / COL;
                float gx = o[((size_t)b * (2 * NJ) + j) * CC + am];
                float gy = o[((size_t)b * (2 * NJ) + NJ + j) * CC + am];
                float x2dx = gx + (float)x2 * scale;
                float x2dy = gy + (float)y2 * scale;

                const int am3 = bi3;
                const int z3 = am3 / CC; const int r3 = am3 - z3 * CC;
                const int y3 = r3 / COL; const int x3 = r3 - y3 * COL;
                size_t base3 = (size_t)b * (3 * NJ * CC3) + (size_t)j * CC3 + am3;
                float g0 = o3D[base3];
                float g1 = o3D[base3 + (size_t)NJ * CC3];
                float g2 = o3D[base3 + (size_t)(2 * NJ) * CC3];
                float x3dx = g0 + (float)x3 * scale;
                float x3dy = g1 + (float)y3 * scale;
                float x3dz = g2 + (float)(z3 - 7) * scale;
                if (vis && !valid2d) { x3dx = 0.f; x3dy = 0.f; x3dz = 0.f; }

                float d2x = (x2dx - tx) * vf0;
                float d2y = (x2dy - ty) * vf1;
                float s2 = d2x * d2x + d2y * d2y;

                float d4x = (x3dx - t3x) * vf0;
                float d4y = (x3dy - t3y) * vf1;
                float d4z = (x3dz - t3z) * vf2;
                float s4 = d4x * d4x + d4y * d4y + d4z * d4z;

                p0 = jm ? s1 : 0.f;
                p1 = s2;
                p2 = jm ? s3 : 0.f;
                p3 = s4;
                p4 = jm ? 1.0f : 0.0f;
                p5 = vf0 + vf1 + vf2;
            }
        }
    }

    if (lane == 0) {
        warr[wv][0] = p0; warr[wv][1] = p1; warr[wv][2] = p2;
        warr[wv][3] = p3; warr[wv][4] = p4; warr[wv][5] = p5;
    }
    __syncthreads();

    if (threadIdx.x == 0) {
        float b0 = ((warr[0][0] + warr[1][0]) + warr[2][0]) + warr[3][0];
        float b1 = ((warr[0][1] + warr[1][1]) + warr[2][1]) + warr[3][1];
        float b2 = ((warr[0][2] + warr[1][2]) + warr[2][2]) + warr[3][2];
        float b3 = ((warr[0][3] + warr[1][3]) + warr[2][3]) + warr[3][3];
        float b4 = ((warr[0][4] + warr[1][4]) + warr[2][4]) + warr[3][4];
        float b5 = ((warr[0][5] + warr[1][5]) + warr[2][5]) + warr[3][5];
        *(float4*)(part + (size_t)blockIdx.x * 8)     = make_float4(b0, b1, b2, b3);
        *(float4*)(part + (size_t)blockIdx.x * 8 + 4) = make_float4(b4, b5, 0.f, 0.f);
        __threadfence();                                  // release partials (device scope)
        unsigned old = atomicAdd(counter, 1u);            // device-scope RMW
        lastFlag = (old == (unsigned)(nblocks - 1)) ? 1 : 0;
    }
    __syncthreads();
    if (!lastFlag) return;

    // ---------- last block: final deterministic tree reduction ----------
    __threadfence();                                      // acquire partials
    const int tid = threadIdx.x;
    double a0 = 0, a1 = 0, a2 = 0, a3 = 0, a4 = 0, a5 = 0;
    for (int p = tid; p < nblocks; p += 256) {
        const float4 q0 = *(const float4*)(part + (size_t)p * 8);
        const float4 q1 = *(const float4*)(part + (size_t)p * 8 + 4);
        a0 += (double)q0.x; a1 += (double)q0.y; a2 += (double)q0.z; a3 += (double)q0.w;
        a4 += (double)q1.x; a5 += (double)q1.y;
    }

    #pragma unroll
    for (int off = 32; off > 0; off >>= 1) {
        a0 += __shfl_down(a0, off);
        a1 += __shfl_down(a1, off);
        a2 += __shfl_down(a2, off);
        a3 += __shfl_down(a3, off);
        a4 += __shfl_down(a4, off);
        a5 += __shfl_down(a5, off);
    }

    __shared__ double ws2[4][6];
    const int wave = tid >> 6;
    if ((tid & 63) == 0) {
        ws2[wave][0] = a0; ws2[wave][1] = a1; ws2[wave][2] = a2;
        ws2[wave][3] = a3; ws2[wave][4] = a4; ws2[wave][5] = a5;
    }
    __syncthreads();

    if (tid == 0) {
        #pragma unroll
        for (int w = 1; w < 4; ++w) {
            a0 += ws2[w][0]; a1 += ws2[w][1]; a2 += ws2[w][2];
            a3 += ws2[w][3]; a4 += ws2[w][4]; a5 += ws2[w][5];
        }
        double cnt = a4;
        double Nv  = a5 / 3.0;
        float d1 = (float)(sqrt(a0) / cnt);
        float d2 = (float)(sqrt(a1) / Nv);
        float d3 = (float)(sqrt(a2) / cnt);
        float d4 = (float)(sqrt(a3) / Nv);
        out[0] = d1 + d2 + d3 + d4;
    }
}

extern "C" void kernel_launch(void* const* d_in, const int* in_sizes, int n_in,
                              void* d_out, int out_size, void* d_ws, size_t ws_size,
                              hipStream_t stream)
{
    const float* o   = (const float*)d_in[0];
    const float* h   = (const float*)d_in[1];
    const float* o3D = (const float*)d_in[2];
    const float* h3D = (const float*)d_in[3];
    const float* t   = (const float*)d_in[4];
    const float* t3D = (const float*)d_in[5];
    const float* v   = (const float*)d_in[6];

    const int B = in_sizes[1] / (NJ * CC);
    const int npairs  = B * NJ;
    const int nblocks = (npairs + PPB - 1) / PPB;

    float* part = (float*)d_ws;                                   // nblocks * 8 floats
    unsigned int* counter = (unsigned int*)((char*)d_ws + (size_t)nblocks * 8 * sizeof(float));

    hipMemsetAsync(counter, 0, sizeof(unsigned int), stream);
    msed_fused_kernel<<<nblocks, 256, 0, stream>>>(o, h, o3D, h3D, t, t3D, v,
                                                   part, counter, (float*)d_out,
                                                   npairs, nblocks);
}

// Round 5
// 24.046 us; speedup vs baseline: 2.3864x; 2.3864x over previous
//
#include <hip/hip_runtime.h>
#include <float.h>
#include <math.h>

#define NJ   24
#define COL  14
#define CC   196        // COL*COL
#define CC3  2744       // COL^3
#define NV4_3D 686      // CC3/4
#define NV4_2D 49       // CC/4
#define TMPW 3
#define PPB  4          // pairs (waves) per block

// Kernel 1: one wave per (b,j) pair, 4 pairs per 256-thread block.
// Identity: sum_e (h[e]-tt[e])^2 = sum_e h^2 - sum_window g*(2h-g)  (gated).
// Block combines its 4 per-wave partials in LDS -> one 32B f32 partial/block.
__global__ __launch_bounds__(256)
void msed_pair_kernel(const float* __restrict__ o,
                      const float* __restrict__ h,
                      const float* __restrict__ o3D,
                      const float* __restrict__ h3D,
                      const float* __restrict__ t,
                      const float* __restrict__ t3D,
                      const float* __restrict__ v,
                      float* __restrict__ part,      // nblocks * 8 floats
                      int npairs)
{
    const int wv   = threadIdx.x >> 6;
    const int lane = threadIdx.x & 63;
    const int pair = blockIdx.x * PPB + wv;

    __shared__ float warr[PPB][6];

    float p0 = 0.f, p1 = 0.f, p2 = 0.f, p3 = 0.f, p4 = 0.f, p5 = 0.f;

    if (pair < npairs) {
        // ---- scalar prologue (wave-uniform) ----
        const float tx  = t[pair * 2 + 0];
        const float ty  = t[pair * 2 + 1];
        const float t3x = t3D[pair * 3 + 0];
        const float t3y = t3D[pair * 3 + 1];
        const float t3z = t3D[pair * 3 + 2];
        const float v0  = v[pair * 3 + 0];
        const float v1  = v[pair * 3 + 1];
        const float v2c = v[pair * 3 + 2];
        const bool vis = (v0 == 1.0f);

        const int mux = (int)floorf(tx * (float)COL + 0.5f);
        const int muy = (int)floorf(ty * (float)COL + 0.5f);
        const bool valid2d = !((mux - TMPW >= COL) || (muy - TMPW >= COL) ||
                               (mux + TMPW + 1 <= 0) || (muy + TMPW + 1 <= 0));

        const int m3x = (int)floorf(t3x * (float)COL + 0.5f);
        const int m3y = (int)floorf(t3y * (float)COL + 0.5f);
        const int m3z = (int)floorf(t3z * (float)COL + 7.0f + 0.5f);
        const bool valid3d = !((m3x - TMPW >= COL) || (m3y - TMPW >= COL) || (m3z - TMPW >= COL) ||
                               (m3x + TMPW + 1 < 0) || (m3y + TMPW + 1 < 0) || (m3z + TMPW + 1 < 0));

        const float keep = vis ? ((valid2d && valid3d) ? 1.0f : 0.0f) : 1.0f;
        const float vf0 = v0 * keep, vf1 = v1 * keep, vf2 = v2c * keep;
        const bool jm     = (vf0 != 0.0f);
        const bool active = jm || (vf1 != 0.0f) || (vf2 != 0.0f);
        const bool gate2  = vis && valid2d;
        const bool gate3  = vis && valid2d && valid3d;

        if (active) {
            // ---- streaming 3D: sum h^2 + argmax (no per-element decode) ----
            const float4* hp3 = (const float4*)(h3D + (size_t)pair * CC3);
            float s3 = 0.0f;
            float bv3 = -FLT_MAX; int bi3 = 0x7FFFFFFF;
            #pragma unroll
            for (int u = 0; u < 11; ++u) {
                const int i = lane + (u << 6);
                const bool valid = (u < 10) || (lane < (NV4_3D - 640));
                const int ic = valid ? i : lane;
                float4 q = hp3[ic];
                float vals[4] = {q.x, q.y, q.z, q.w};
                const int e0 = ic * 4;
                #pragma unroll
                for (int c = 0; c < 4; ++c) {
                    float hv = vals[c];
                    if (valid) {
                        s3 += hv * hv;
                        if (hv > bv3) { bv3 = hv; bi3 = e0 + c; }  // per-lane e increasing
                    }
                }
            }

            // ---- streaming 2D ----
            float s1 = 0.0f;
            float bv2 = -FLT_MAX; int bi2 = 0x7FFFFFFF;
            if (lane < NV4_2D) {
                const float4* hp2 = (const float4*)(h + (size_t)pair * CC);
                float4 q = hp2[lane];
                float vals[4] = {q.x, q.y, q.z, q.w};
                const int e0 = lane * 4;
                #pragma unroll
                for (int c = 0; c < 4; ++c) {
                    float hv = vals[c];
                    s1 += hv * hv;
                    if (hv > bv2) { bv2 = hv; bi2 = e0 + c; }
                }
            }

            // ---- gaussian window corrections (L1/L2-hot gathers) ----
            if (lane < 49) {
                const int dx = lane % 7 - TMPW;
                const int dy = lane / 7 - TMPW;
                const float gxy = __expf(-0.5f * (float)(dx * dx + dy * dy));

                if (gate2) {
                    const int x = mux + dx, y = muy + dy;
                    if ((unsigned)x < COL && (unsigned)y < COL) {
                        const float wh = h[(size_t)pair * CC + y * COL + x];
                        s1 += gxy * (gxy - 2.0f * wh);   // (h-g)^2 - h^2
                    }
                }
                if (gate3) {
                    const int x = m3x + dx, y = m3y + dy;
                    if ((unsigned)x < COL && (unsigned)y < COL) {
                        const float* base = h3D + (size_t)pair * CC3 + y * COL + x;
                        #pragma unroll
                        for (int dz = -TMPW; dz <= TMPW; ++dz) {
                            const int z = m3z + dz;
                            if ((unsigned)z < COL) {
                                const float g = gxy * __expf(-0.5f * (float)(dz * dz));
                                const float wh = base[z * CC];
                                s3 += g * (g - 2.0f * wh);
                            }
                        }
                    }
                }
            }

            // ---- single-wave shuffle reduction ----
            #pragma unroll
            for (int off = 32; off > 0; off >>= 1) {
                s3 += __shfl_down(s3, off);
                s1 += __shfl_down(s1, off);
                float ov = __shfl_down(bv3, off); int oi = __shfl_down(bi3, off);
                if (ov > bv3 || (ov == bv3 && oi < bi3)) { bv3 = ov; bi3 = oi; }
                float ow = __shfl_down(bv2, off); int oj = __shfl_down(bi2, off);
                if (ow > bv2 || (ow == bv2 && oj < bi2)) { bv2 = ow; bi2 = oj; }
            }

            if (lane == 0) {
                const int b = pair / NJ;
                const int j = pair - b * NJ;
                const float scale = 1.0f / (float)COL;

                const int am = bi2;
                const int x2 = am % COL, y2 = am / COL;
                float gx = o[((size_t)b * (2 * NJ) + j) * CC + am];
                float gy = o[((size_t)b * (2 * NJ) + NJ + j) * CC + am];
                float x2dx = gx + (float)x2 * scale;
                float x2dy = gy + (float)y2 * scale;

                const int am3 = bi3;
                const int z3 = am3 / CC; const int r3 = am3 - z3 * CC;
                const int y3 = r3 / COL; const int x3 = r3 - y3 * COL;
                size_t base3 = (size_t)b * (3 * NJ * CC3) + (size_t)j * CC3 + am3;
                float g0 = o3D[base3];
                float g1 = o3D[base3 + (size_t)NJ * CC3];
                float g2 = o3D[base3 + (size_t)(2 * NJ) * CC3];
                float x3dx = g0 + (float)x3 * scale;
                float x3dy = g1 + (float)y3 * scale;
                float x3dz = g2 + (float)(z3 - 7) * scale;
                if (vis && !valid2d) { x3dx = 0.f; x3dy = 0.f; x3dz = 0.f; }

                float d2x = (x2dx - tx) * vf0;
                float d2y = (x2dy - ty) * vf1;
                float s2 = d2x * d2x + d2y * d2y;

                float d4x = (x3dx - t3x) * vf0;
                float d4y = (x3dy - t3y) * vf1;
                float d4z = (x3dz - t3z) * vf2;
                float s4 = d4x * d4x + d4y * d4y + d4z * d4z;

                p0 = jm ? s1 : 0.f;
                p1 = s2;
                p2 = jm ? s3 : 0.f;
                p3 = s4;
                p4 = jm ? 1.0f : 0.0f;
                p5 = vf0 + vf1 + vf2;
            }
        }
    }

    if (lane == 0) {
        warr[wv][0] = p0; warr[wv][1] = p1; warr[wv][2] = p2;
        warr[wv][3] = p3; warr[wv][4] = p4; warr[wv][5] = p5;
    }
    __syncthreads();

    if (threadIdx.x == 0) {
        float b0 = ((warr[0][0] + warr[1][0]) + warr[2][0]) + warr[3][0];
        float b1 = ((warr[0][1] + warr[1][1]) + warr[2][1]) + warr[3][1];
        float b2 = ((warr[0][2] + warr[1][2]) + warr[2][2]) + warr[3][2];
        float b3 = ((warr[0][3] + warr[1][3]) + warr[2][3]) + warr[3][3];
        float b4 = ((warr[0][4] + warr[1][4]) + warr[2][4]) + warr[3][4];
        float b5 = ((warr[0][5] + warr[1][5]) + warr[2][5]) + warr[3][5];
        *(float4*)(part + (size_t)blockIdx.x * 8)     = make_float4(b0, b1, b2, b3);
        *(float4*)(part + (size_t)blockIdx.x * 8 + 4) = make_float4(b4, b5, 0.f, 0.f);
    }
}

// Kernel 2: deterministic f64 tree reduction over nblocks x 8 partials.
__global__ __launch_bounds__(1024)
void msed_reduce_kernel(const float* __restrict__ part, int nblocks,
                        float* __restrict__ out)
{
    const int tid = threadIdx.x;
    double a0 = 0, a1 = 0, a2 = 0, a3 = 0, a4 = 0, a5 = 0;
    for (int p = tid; p < nblocks; p += 1024) {
        const float4 q0 = *(const float4*)(part + (size_t)p * 8);
        const float4 q1 = *(const float4*)(part + (size_t)p * 8 + 4);
        a0 += (double)q0.x; a1 += (double)q0.y; a2 += (double)q0.z; a3 += (double)q0.w;
        a4 += (double)q1.x; a5 += (double)q1.y;
    }

    #pragma unroll
    for (int off = 32; off > 0; off >>= 1) {
        a0 += __shfl_down(a0, off);
        a1 += __shfl_down(a1, off);
        a2 += __shfl_down(a2, off);
        a3 += __shfl_down(a3, off);
        a4 += __shfl_down(a4, off);
        a5 += __shfl_down(a5, off);
    }

    __shared__ double ws[16][6];
    const int wave = tid >> 6;
    if ((tid & 63) == 0) {
        ws[wave][0] = a0; ws[wave][1] = a1; ws[wave][2] = a2;
        ws[wave][3] = a3; ws[wave][4] = a4; ws[wave][5] = a5;
    }
    __syncthreads();

    if (tid == 0) {
        #pragma unroll
        for (int w = 1; w < 16; ++w) {
            a0 += ws[w][0]; a1 += ws[w][1]; a2 += ws[w][2];
            a3 += ws[w][3]; a4 += ws[w][4]; a5 += ws[w][5];
        }
        double cnt = a4;
        double Nv  = a5 / 3.0;
        float d1 = (float)(sqrt(a0) / cnt);
        float d2 = (float)(sqrt(a1) / Nv);
        float d3 = (float)(sqrt(a2) / cnt);
        float d4 = (float)(sqrt(a3) / Nv);
        out[0] = d1 + d2 + d3 + d4;
    }
}

extern "C" void kernel_launch(void* const* d_in, const int* in_sizes, int n_in,
                              void* d_out, int out_size, void* d_ws, size_t ws_size,
                              hipStream_t stream)
{
    const float* o   = (const float*)d_in[0];
    const float* h   = (const float*)d_in[1];
    const float* o3D = (const float*)d_in[2];
    const float* h3D = (const float*)d_in[3];
    const float* t   = (const float*)d_in[4];
    const float* t3D = (const float*)d_in[5];
    const float* v   = (const float*)d_in[6];

    const int B = in_sizes[1] / (NJ * CC);
    const int npairs  = B * NJ;
    const int nblocks = (npairs + PPB - 1) / PPB;

    float* part = (float*)d_ws;      // nblocks * 8 floats

    msed_pair_kernel<<<nblocks, 256, 0, stream>>>(o, h, o3D, h3D, t, t3D, v, part, npairs);
    msed_reduce_kernel<<<1, 1024, 0, stream>>>(part, nblocks, (float*)d_out);
}

// Round 6
// 23.768 us; speedup vs baseline: 2.4143x; 1.0117x over previous
//
#include <hip/hip_runtime.h>
#include <float.h>
#include <math.h>

#define NJ   24
#define COL  14
#define CC   196        // COL*COL
#define CC3  2744       // COL^3
#define NV4_3D 686      // CC3/4
#define NV4_2D 49       // CC/4
#define TMPW 3
#define PPB  4          // pairs (waves) per block

// Kernel 1: one wave per (b,j) pair, 4 pairs per 256-thread block.
// Identity: sum_e (h[e]-tt[e])^2 = sum_e h^2 - sum_window g*(2h-g)  (gated).
// NEW (R5): each wave stages its h3D/h slice into LDS during the streaming
// pass; the gaussian-window corrections read LDS instead of issuing 8
// divergent global gather instructions per wave (address-processing tax on
// the per-CU TA pipe, which profiling showed is occupancy-invariant).
__global__ __launch_bounds__(256)
void msed_pair_kernel(const float* __restrict__ o,
                      const float* __restrict__ h,
                      const float* __restrict__ o3D,
                      const float* __restrict__ h3D,
                      const float* __restrict__ t,
                      const float* __restrict__ t3D,
                      const float* __restrict__ v,
                      float* __restrict__ part,      // nblocks * 8 floats
                      int npairs)
{
    const int wv   = threadIdx.x >> 6;
    const int lane = threadIdx.x & 63;
    const int pair = blockIdx.x * PPB + wv;

    __shared__ float s3buf[PPB][CC3];   // 4 * 10976 B
    __shared__ float s2buf[PPB][CC];    // 4 *   784 B
    __shared__ float warr[PPB][6];

    float p0 = 0.f, p1 = 0.f, p2 = 0.f, p3 = 0.f, p4 = 0.f, p5 = 0.f;

    // per-wave state carried across the barrier
    bool active = false, jm = false, vis = false, valid2d = false;
    bool gate2 = false, gate3 = false;
    int mux = 0, muy = 0, m3x = 0, m3y = 0, m3z = 0;
    float tx = 0.f, ty = 0.f, t3x = 0.f, t3y = 0.f, t3z = 0.f;
    float vf0 = 0.f, vf1 = 0.f, vf2 = 0.f;
    float s1 = 0.f, s3 = 0.f;
    float bv2 = -FLT_MAX, bv3 = -FLT_MAX;
    int bi2 = 0x7FFFFFFF, bi3 = 0x7FFFFFFF;

    if (pair < npairs) {
        // ---- scalar prologue (wave-uniform) ----
        tx  = t[pair * 2 + 0];
        ty  = t[pair * 2 + 1];
        t3x = t3D[pair * 3 + 0];
        t3y = t3D[pair * 3 + 1];
        t3z = t3D[pair * 3 + 2];
        const float v0  = v[pair * 3 + 0];
        const float v1  = v[pair * 3 + 1];
        const float v2c = v[pair * 3 + 2];
        vis = (v0 == 1.0f);

        mux = (int)floorf(tx * (float)COL + 0.5f);
        muy = (int)floorf(ty * (float)COL + 0.5f);
        valid2d = !((mux - TMPW >= COL) || (muy - TMPW >= COL) ||
                    (mux + TMPW + 1 <= 0) || (muy + TMPW + 1 <= 0));

        m3x = (int)floorf(t3x * (float)COL + 0.5f);
        m3y = (int)floorf(t3y * (float)COL + 0.5f);
        m3z = (int)floorf(t3z * (float)COL + 7.0f + 0.5f);
        const bool valid3d = !((m3x - TMPW >= COL) || (m3y - TMPW >= COL) || (m3z - TMPW >= COL) ||
                               (m3x + TMPW + 1 < 0) || (m3y + TMPW + 1 < 0) || (m3z + TMPW + 1 < 0));

        const float keep = vis ? ((valid2d && valid3d) ? 1.0f : 0.0f) : 1.0f;
        vf0 = v0 * keep; vf1 = v1 * keep; vf2 = v2c * keep;
        jm     = (vf0 != 0.0f);
        active = jm || (vf1 != 0.0f) || (vf2 != 0.0f);
        gate2  = vis && valid2d;
        gate3  = vis && valid2d && valid3d;

        if (active) {
            // ---- streaming 3D: sum h^2 + argmax + LDS staging ----
            const float4* hp3 = (const float4*)(h3D + (size_t)pair * CC3);
            #pragma unroll
            for (int u = 0; u < 11; ++u) {
                const int i = lane + (u << 6);
                const bool valid = (u < 10) || (lane < (NV4_3D - 640));
                const int ic = valid ? i : lane;
                float4 q = hp3[ic];
                *(float4*)&s3buf[wv][ic * 4] = q;          // LDS stage (dup writes on tail are benign)
                float vals[4] = {q.x, q.y, q.z, q.w};
                const int e0 = ic * 4;
                #pragma unroll
                for (int c = 0; c < 4; ++c) {
                    float hv = vals[c];
                    if (valid) {
                        s3 += hv * hv;
                        if (hv > bv3) { bv3 = hv; bi3 = e0 + c; }  // per-lane e increasing
                    }
                }
            }

            // ---- streaming 2D + LDS staging ----
            if (lane < NV4_2D) {
                const float4* hp2 = (const float4*)(h + (size_t)pair * CC);
                float4 q = hp2[lane];
                *(float4*)&s2buf[wv][lane * 4] = q;
                float vals[4] = {q.x, q.y, q.z, q.w};
                const int e0 = lane * 4;
                #pragma unroll
                for (int c = 0; c < 4; ++c) {
                    float hv = vals[c];
                    s1 += hv * hv;
                    if (hv > bv2) { bv2 = hv; bi2 = e0 + c; }
                }
            }
        }
    }

    __syncthreads();   // order LDS staging before window reads (and compiler fence)

    if (active) {
        // ---- gaussian window corrections, now from LDS ----
        if (lane < 49) {
            const int dx = lane % 7 - TMPW;
            const int dy = lane / 7 - TMPW;
            const float gxy = __expf(-0.5f * (float)(dx * dx + dy * dy));

            if (gate2) {
                const int x = mux + dx, y = muy + dy;
                if ((unsigned)x < COL && (unsigned)y < COL) {
                    const float wh = s2buf[wv][y * COL + x];
                    s1 += gxy * (gxy - 2.0f * wh);   // (h-g)^2 - h^2
                }
            }
            if (gate3) {
                const int x = m3x + dx, y = m3y + dy;
                if ((unsigned)x < COL && (unsigned)y < COL) {
                    const int base = y * COL + x;
                    #pragma unroll
                    for (int dz = -TMPW; dz <= TMPW; ++dz) {
                        const int z = m3z + dz;
                        if ((unsigned)z < COL) {
                            const float g = gxy * __expf(-0.5f * (float)(dz * dz));
                            const float wh = s3buf[wv][z * CC + base];
                            s3 += g * (g - 2.0f * wh);
                        }
                    }
                }
            }
        }

        // ---- single-wave shuffle reduction ----
        #pragma unroll
        for (int off = 32; off > 0; off >>= 1) {
            s3 += __shfl_down(s3, off);
            s1 += __shfl_down(s1, off);
            float ov = __shfl_down(bv3, off); int oi = __shfl_down(bi3, off);
            if (ov > bv3 || (ov == bv3 && oi < bi3)) { bv3 = ov; bi3 = oi; }
            float ow = __shfl_down(bv2, off); int oj = __shfl_down(bi2, off);
            if (ow > bv2 || (ow == bv2 && oj < bi2)) { bv2 = ow; bi2 = oj; }
        }

        if (lane == 0) {
            const int b = pair / NJ;
            const int j = pair - b * NJ;
            const float scale = 1.0f / (float)COL;

            const int am = bi2;
            const int x2 = am % COL, y2 = am / COL;
            float gx = o[((size_t)b * (2 * NJ) + j) * CC + am];
            float gy = o[((size_t)b * (2 * NJ) + NJ + j) * CC + am];
            float x2dx = gx + (float)x2 * scale;
            float x2dy = gy + (float)y2 * scale;

            const int am3 = bi3;
            const int z3 = am3 / CC; const int r3 = am3 - z3 * CC;
            const int y3 = r3 / COL; const int x3 = r3 - y3 * COL;
            size_t base3 = (size_t)b * (3 * NJ * CC3) + (size_t)j * CC3 + am3;
            float g0 = o3D[base3];
            float g1 = o3D[base3 + (size_t)NJ * CC3];
            float g2 = o3D[base3 + (size_t)(2 * NJ) * CC3];
            float x3dx = g0 + (float)x3 * scale;
            float x3dy = g1 + (float)y3 * scale;
            float x3dz = g2 + (float)(z3 - 7) * scale;
            if (vis && !valid2d) { x3dx = 0.f; x3dy = 0.f; x3dz = 0.f; }

            float d2x = (x2dx - tx) * vf0;
            float d2y = (x2dy - ty) * vf1;
            float s2 = d2x * d2x + d2y * d2y;

            float d4x = (x3dx - t3x) * vf0;
            float d4y = (x3dy - t3y) * vf1;
            float d4z = (x3dz - t3z) * vf2;
            float s4 = d4x * d4x + d4y * d4y + d4z * d4z;

            p0 = jm ? s1 : 0.f;
            p1 = s2;
            p2 = jm ? s3 : 0.f;
            p3 = s4;
            p4 = jm ? 1.0f : 0.0f;
            p5 = vf0 + vf1 + vf2;
        }
    }

    if (lane == 0) {
        warr[wv][0] = p0; warr[wv][1] = p1; warr[wv][2] = p2;
        warr[wv][3] = p3; warr[wv][4] = p4; warr[wv][5] = p5;
    }
    __syncthreads();

    if (threadIdx.x == 0) {
        float b0 = ((warr[0][0] + warr[1][0]) + warr[2][0]) + warr[3][0];
        float b1 = ((warr[0][1] + warr[1][1]) + warr[2][1]) + warr[3][1];
        float b2 = ((warr[0][2] + warr[1][2]) + warr[2][2]) + warr[3][2];
        float b3 = ((warr[0][3] + warr[1][3]) + warr[2][3]) + warr[3][3];
        float b4 = ((warr[0][4] + warr[1][4]) + warr[2][4]) + warr[3][4];
        float b5 = ((warr[0][5] + warr[1][5]) + warr[2][5]) + warr[3][5];
        *(float4*)(part + (size_t)blockIdx.x * 8)     = make_float4(b0, b1, b2, b3);
        *(float4*)(part + (size_t)blockIdx.x * 8 + 4) = make_float4(b4, b5, 0.f, 0.f);
    }
}

// Kernel 2: deterministic f64 tree reduction over nblocks x 8 partials.
__global__ __launch_bounds__(1024)
void msed_reduce_kernel(const float* __restrict__ part, int nblocks,
                        float* __restrict__ out)
{
    const int tid = threadIdx.x;
    double a0 = 0, a1 = 0, a2 = 0, a3 = 0, a4 = 0, a5 = 0;
    for (int p = tid; p < nblocks; p += 1024) {
        const float4 q0 = *(const float4*)(part + (size_t)p * 8);
        const float4 q1 = *(const float4*)(part + (size_t)p * 8 + 4);
        a0 += (double)q0.x; a1 += (double)q0.y; a2 += (double)q0.z; a3 += (double)q0.w;
        a4 += (double)q1.x; a5 += (double)q1.y;
    }

    #pragma unroll
    for (int off = 32; off > 0; off >>= 1) {
        a0 += __shfl_down(a0, off);
        a1 += __shfl_down(a1, off);
        a2 += __shfl_down(a2, off);
        a3 += __shfl_down(a3, off);
        a4 += __shfl_down(a4, off);
        a5 += __shfl_down(a5, off);
    }

    __shared__ double ws[16][6];
    const int wave = tid >> 6;
    if ((tid & 63) == 0) {
        ws[wave][0] = a0; ws[wave][1] = a1; ws[wave][2] = a2;
        ws[wave][3] = a3; ws[wave][4] = a4; ws[wave][5] = a5;
    }
    __syncthreads();

    if (tid == 0) {
        #pragma unroll
        for (int w = 1; w < 16; ++w) {
            a0 += ws[w][0]; a1 += ws[w][1]; a2 += ws[w][2];
            a3 += ws[w][3]; a4 += ws[w][4]; a5 += ws[w][5];
        }
        double cnt = a4;
        double Nv  = a5 / 3.0;
        float d1 = (float)(sqrt(a0) / cnt);
        float d2 = (float)(sqrt(a1) / Nv);
        float d3 = (float)(sqrt(a2) / cnt);
        float d4 = (float)(sqrt(a3) / Nv);
        out[0] = d1 + d2 + d3 + d4;
    }
}

extern "C" void kernel_launch(void* const* d_in, const int* in_sizes, int n_in,
                              void* d_out, int out_size, void* d_ws, size_t ws_size,
                              hipStream_t stream)
{
    const float* o   = (const float*)d_in[0];
    const float* h   = (const float*)d_in[1];
    const float* o3D = (const float*)d_in[2];
    const float* h3D = (const float*)d_in[3];
    const float* t   = (const float*)d_in[4];
    const float* t3D = (const float*)d_in[5];
    const float* v   = (const float*)d_in[6];

    const int B = in_sizes[1] / (NJ * CC);
    const int npairs  = B * NJ;
    const int nblocks = (npairs + PPB - 1) / PPB;

    float* part = (float*)d_ws;      // nblocks * 8 floats

    msed_pair_kernel<<<nblocks, 256, 0, stream>>>(o, h, o3D, h3D, t, t3D, v, part, npairs);
    msed_reduce_kernel<<<1, 1024, 0, stream>>>(part, nblocks, (float*)d_out);
}